// Round 13
// baseline (164.210 us; speedup 1.0000x reference)
//
#include <hip/hip_runtime.h>
#include <hip/hip_bf16.h>

typedef __bf16 bf16_t;
typedef bf16_t bf16x8 __attribute__((ext_vector_type(8)));
typedef float f32x16 __attribute__((ext_vector_type(16)));

// 10000^(-i/32) = 10^(-i/8), i = 0..15
constexpr float OMG[16] = {
    1.0f,        0.74989421f, 0.56234133f, 0.42169650f,
    0.31622777f, 0.23713737f, 0.17782794f, 0.13335214f,
    0.1f,        0.074989421f, 0.056234133f, 0.042169650f,
    0.031622777f, 0.023713737f, 0.017782794f, 0.013335214f};

__device__ __forceinline__ f32x16 mfma_bf16(bf16x8 a, bf16x8 b, f32x16 c) {
  return __builtin_amdgcn_mfma_f32_32x32x16_bf16(a, b, c, 0, 0, 0);
}

// packed k-index pk = 32d + 16m2 + (8hi+e)  <->  orig k = 64d + 32m2 + (8hi+e)
__device__ __forceinline__ int orig_k(int pk) {
  return 64 * (pk >> 5) + 32 * ((pk >> 4) & 1) + (pk & 15);
}

// ---- fused prep (113 blocks):
//  0..7  : w1 -> packed+pre-swizzled 64KB image
//  8     : ext image (vlin rank-4 rows) + b1fold
//  9..16 : wp bottom -> wpT2[o][256+kp] transpose
//  17..80: W2'[j][o] = sum_n w2[j][n]*wp[n][o] (fp32) -> wpT2[o][j]
//  81..112: bfold[o] = bp[o] + sum_k b2[k]*wp[k][o]
__global__ __launch_bounds__(256) void prep(
    const float* __restrict__ w1, const float* __restrict__ w2,
    const float* __restrict__ wp, const float* __restrict__ b1,
    const float* __restrict__ b2, const float* __restrict__ bp,
    bf16_t* __restrict__ w1img, bf16_t* __restrict__ wpT2,
    float* __restrict__ bfold, float* __restrict__ b1fold) {
  __shared__ float T[256][33];
  const int bid = blockIdx.x;
  const int tid = threadIdx.x;

  if (bid < 8) {
    const int n0 = bid * 32;
#pragma unroll
    for (int it = 0; it < 16; ++it) {
      const int pk = it * 8 + (tid >> 5);
      T[pk][tid & 31] = w1[orig_k(pk) * 256 + n0 + (tid & 31)];
    }
    __syncthreads();
    const int n_off = tid & 31;
    const int n = n0 + n_off;
#pragma unroll
    for (int q = 0; q < 2; ++q) {
      const int slot = (tid >> 5) + 8 * q;  // 0..15
      bf16x8 v;
#pragma unroll
      for (int e = 0; e < 8; ++e) v[e] = (bf16_t)T[slot * 8 + e][n_off];
      *(bf16x8*)((char*)w1img + n * 256 + ((slot ^ (n & 15)) << 4)) = v;
    }
  } else if (bid == 8) {
    const int n = tid;
    float vl[4];
    float bf1 = b1[n];
#pragma unroll
    for (int d = 0; d < 4; ++d) {
      float s = 0.f;
#pragma unroll
      for (int i = 0; i < 16; ++i)
        s = fmaf(0.01f * OMG[i], w1[(64 * d + 16 + i) * 256 + n], s);
      vl[d] = s;
#pragma unroll
      for (int i = 0; i < 16; ++i) bf1 += w1[(64 * d + 48 + i) * 256 + n];
    }
    bf16_t* ext = w1img + 32768 + n * 16;
#pragma unroll
    for (int e = 0; e < 4; ++e) ext[e] = (bf16_t)vl[e];
#pragma unroll
    for (int e = 4; e < 16; ++e) ext[e] = (bf16_t)0.0f;
    b1fold[n] = bf1;
  } else if (bid < 17) {
    const int band = (bid - 9) * 32;
#pragma unroll
    for (int it = 0; it < 32; ++it)
      T[tid][it] = wp[(256 + band + it) * 256 + tid];
    __syncthreads();
    const int o = tid;
#pragma unroll
    for (int g = 0; g < 4; ++g) {
      bf16x8 v;
#pragma unroll
      for (int e = 0; e < 8; ++e) v[e] = (bf16_t)T[o][g * 8 + e];
      *(bf16x8*)(wpT2 + o * 512 + 256 + band + g * 8) = v;
    }
  } else if (bid < 81) {
    const int t2 = bid - 17;
    const int o0 = (t2 >> 3) * 32, j0 = (t2 & 7) * 32;
#pragma unroll
    for (int it = 0; it < 32; ++it) {
      const int n = it * 8 + (tid >> 5);
      T[n][tid & 31] = wp[n * 256 + o0 + (tid & 31)];
    }
    __syncthreads();
    const int o_off = tid & 31, jb = tid >> 5;
    float a4[4] = {0.f, 0.f, 0.f, 0.f};
    for (int n = 0; n < 256; ++n) {
      const float wv = T[n][o_off];
#pragma unroll
      for (int q = 0; q < 4; ++q)
        a4[q] = fmaf(w2[(j0 + jb + 8 * q) * 256 + n], wv, a4[q]);
    }
#pragma unroll
    for (int q = 0; q < 4; ++q)
      wpT2[(o0 + o_off) * 512 + j0 + jb + 8 * q] = (bf16_t)a4[q];
  } else {
    const int o = (bid - 81) * 8 + (tid >> 5);
    const int kl = (tid & 31) * 8;
    float s = 0.f;
#pragma unroll
    for (int k = 0; k < 8; ++k) s += b2[kl + k] * wp[(kl + k) * 256 + o];
    s += __shfl_xor(s, 16); s += __shfl_xor(s, 8); s += __shfl_xor(s, 4);
    s += __shfl_xor(s, 2); s += __shfl_xor(s, 1);
    if ((tid & 31) == 0) bfold[o] = s + bp[o];
  }
}

// ---- edge kernel: 512 thr = 8 waves = 4 pairs; pair = 1 supernode (x2 seq);
// wave owns 128 out cols (acc[4] = 64 regs). 4 d-steps x {sin,cos} shared-angle
// MFMA groups + rank-4 ext step. Sup-embed folded in. Stage once, 1 barrier.
__global__ __launch_bounds__(512, 4) void edge_mlp(
    const float* __restrict__ pos, const int* __restrict__ sup_idx,
    const int* __restrict__ src_idx,
    const bf16_t* __restrict__ w1img, const float* __restrict__ b1fold,
    bf16_t* __restrict__ cat) {
  __shared__ __attribute__((aligned(16))) bf16_t Bs[36864];  // 72 KiB

  const int tid = threadIdx.x;

  // one-time linear stage of the pre-swizzled image (64KB B' + 8KB ext)
  {
    const bf16x8* src8 = (const bf16x8*)w1img;
    bf16x8* dst8 = (bf16x8*)Bs;
#pragma unroll
    for (int it = 0; it < 9; ++it) {
      const int idx = it * 512 + tid;
      dst8[idx] = src8[idx];
    }
  }

  const int l = tid & 63, w = tid >> 6;
  const int pair = w >> 1, half = w & 1;
  const int hi = l >> 5, lc = l & 31;

  float omg[8];
#pragma unroll
  for (int e = 0; e < 8; ++e) omg[e] = hi ? OMG[8 + e] : OMG[e];

  float bi[4];
#pragma unroll
  for (int nt = 0; nt < 4; ++nt) bi[nt] = b1fold[128 * half + 32 * nt + lc];

  // sup-embed constants for this lane's two columns (col, col+64)
  const int ecol0 = 128 * half + l;
  float eom[2];
  int esc[2], ed[2];
#pragma unroll
  for (int q = 0; q < 2; ++q) {
    const int col = ecol0 + 64 * q;
    const int d = (col >= 84 ? 1 : 0) + (col >= 168 ? 1 : 0);
    const int t3 = col - 84 * d;
    const int sc2 = (t3 >= 42) ? 1 : 0;
    ed[q] = d; esc[q] = sc2;
    eom[q] = __expf(-0.21929381838038533f * (float)(t3 - 42 * sc2));
  }

  __syncthreads();

  const char* Bb = (const char*)Bs;
  const int sxor = (lc & 15) << 4;
  const int rowbase = (128 * half + lc) * 256;  // + nt*8192
  const char* eb = Bb + 65536 + (128 * half + lc) * 32 + hi * 16;

  for (int ss = 0; ss < 2; ++ss) {
    const int s = blockIdx.x * 8 + pair * 2 + ss;
    const int si = sup_idx[s];
    const float spx = pos[si * 3 + 0];
    const float spy = pos[si * 3 + 1];
    const float spz = pos[si * 3 + 2];
    const int srci = src_idx[s * 32 + lc];
    const float dx = spx - pos[srci * 3 + 0];
    const float dy = spy - pos[srci * 3 + 1];
    const float dz = spz - pos[srci * 3 + 2];
    const float mg = sqrtf(dx * dx + dy * dy + dz * dz);
    const float rv[4] = {dx, dy, dz, mg};

    f32x16 acc[4];
#pragma unroll
    for (int nt = 0; nt < 4; ++nt)
#pragma unroll
      for (int p = 0; p < 16; ++p) acc[nt][p] = 0.0f;

    // rank-4 ext step
    {
      bf16x8 aext;
#pragma unroll
      for (int e = 0; e < 8; ++e)
        aext[e] = (hi == 0 && e < 4) ? (bf16_t)rv[e] : (bf16_t)0.0f;
#pragma unroll
      for (int nt = 0; nt < 4; ++nt) {
        bf16x8 be = *(const bf16x8*)(eb + nt * 1024);
        acc[nt] = mfma_bf16(aext, be, acc[nt]);
      }
    }

#pragma unroll
    for (int d = 0; d < 4; ++d) {
      float ang[8];
#pragma unroll
      for (int e = 0; e < 8; ++e) ang[e] = rv[d] * omg[e];
      bf16x8 a_sin, a_cos;
#pragma unroll
      for (int e = 0; e < 8; ++e) a_sin[e] = (bf16_t)__sinf(ang[e]);
#pragma unroll
      for (int e = 0; e < 8; ++e) a_cos[e] = (bf16_t)__cosf(ang[e]);

      const int ko_sin = ((4 * d + hi) << 4) ^ sxor;
      const int ko_cos = ((4 * d + 2 + hi) << 4) ^ sxor;
      {
        bf16x8 b0 = *(const bf16x8*)(Bb + rowbase + 0 * 8192 + ko_sin);
        bf16x8 b1_ = *(const bf16x8*)(Bb + rowbase + 1 * 8192 + ko_sin);
        bf16x8 b2_ = *(const bf16x8*)(Bb + rowbase + 2 * 8192 + ko_sin);
        bf16x8 b3 = *(const bf16x8*)(Bb + rowbase + 3 * 8192 + ko_sin);
        acc[0] = mfma_bf16(a_sin, b0, acc[0]);
        acc[1] = mfma_bf16(a_sin, b1_, acc[1]);
        acc[2] = mfma_bf16(a_sin, b2_, acc[2]);
        acc[3] = mfma_bf16(a_sin, b3, acc[3]);
      }
      {
        bf16x8 b0 = *(const bf16x8*)(Bb + rowbase + 0 * 8192 + ko_cos);
        bf16x8 b1_ = *(const bf16x8*)(Bb + rowbase + 1 * 8192 + ko_cos);
        bf16x8 b2_ = *(const bf16x8*)(Bb + rowbase + 2 * 8192 + ko_cos);
        bf16x8 b3 = *(const bf16x8*)(Bb + rowbase + 3 * 8192 + ko_cos);
        acc[0] = mfma_bf16(a_cos, b0, acc[0]);
        acc[1] = mfma_bf16(a_cos, b1_, acc[1]);
        acc[2] = mfma_bf16(a_cos, b2_, acc[2]);
        acc[3] = mfma_bf16(a_cos, b3, acc[3]);
      }
    }

    // trimmed gelu + segment mean -> cat[s, 128*half .. +128)
    const float C2 = -0.10296644f, C0 = -2.3022765f;
#pragma unroll
    for (int nt = 0; nt < 4; ++nt) {
      float ssum = 0.0f;
#pragma unroll
      for (int p = 0; p < 16; p += 2) {
        const float x0 = acc[nt][p] + bi[nt];
        const float x1 = acc[nt][p + 1] + bi[nt];
        const float t0 = fmaf(x0 * x0, C2, C0), t1 = fmaf(x1 * x1, C2, C0);
        const float e0 = exp2f(x0 * t0), e1 = exp2f(x1 * t1);
        const float r0 = __builtin_amdgcn_rcpf(e0 + 1.0f);
        const float r1 = __builtin_amdgcn_rcpf(e1 + 1.0f);
        ssum = fmaf(x0, r0, ssum);
        ssum = fmaf(x1, r1, ssum);
      }
      ssum += __shfl_xor(ssum, 32);
      if (hi == 0)
        cat[s * 512 + 128 * half + 32 * nt + lc] = (bf16_t)(ssum * 0.03125f);
    }

    // sup-embed: this lane's two columns -> cat[s, 256+col]
#pragma unroll
    for (int q = 0; q < 2; ++q) {
      const int col = ecol0 + 64 * q;
      float v = 0.0f;
      if (col < 252) {
        const float pd = (ed[q] == 0) ? spx : ((ed[q] == 1) ? spy : spz);
        const float ang = pd * eom[q];
        v = esc[q] ? __cosf(ang) : __sinf(ang);
      }
      cat[s * 512 + 256 + col] = (bf16_t)v;
    }
  }
}

// ---- fused projection: out = cat(8192x512) @ wpT2^T + bfold -> fp32
__global__ __launch_bounds__(256) void proj(
    const bf16_t* __restrict__ cat, const bf16_t* __restrict__ wpT2,
    const float* __restrict__ bfold, float* __restrict__ out) {
  const int tid = threadIdx.x;
  const int l = tid & 63, w = tid >> 6;
  const int hi = l >> 5, lc = l & 31;
  const int rm = blockIdx.x * 32;
  const int cn = blockIdx.y * 128 + w * 32;
  const int r0 = rm + lc;
  const int c0 = cn + lc;

  f32x16 a0;
#pragma unroll
  for (int p = 0; p < 16; ++p) a0[p] = 0.f;
#pragma unroll 8
  for (int kk = 0; kk < 32; ++kk) {
    int k0 = kk * 16 + 8 * hi;
    bf16x8 fa0 = *(const bf16x8*)(cat + r0 * 512 + k0);
    bf16x8 fb = *(const bf16x8*)(wpT2 + c0 * 512 + k0);
    a0 = mfma_bf16(fa0, fb, a0);
  }
  float bias = bfold[c0];
#pragma unroll
  for (int rr = 0; rr < 16; ++rr) {
    int rowo = (rr & 3) + 8 * (rr >> 2) + 4 * hi;
    out[(rm + rowo) * 256 + c0] = a0[rr] + bias;
  }
}

extern "C" void kernel_launch(void* const* d_in, const int* in_sizes, int n_in,
                              void* d_out, int out_size, void* d_ws, size_t ws_size,
                              hipStream_t stream) {
  const float* pos = (const float*)d_in[0];
  const int* sup_idx = (const int*)d_in[1];
  const int* src_idx = (const int*)d_in[2];
  // d_in[3] = dst_seg: repeat(arange(NSUP), DEG) by construction; not needed
  const float* w1 = (const float*)d_in[4];
  const float* b1 = (const float*)d_in[5];
  const float* w2 = (const float*)d_in[6];
  const float* b2 = (const float*)d_in[7];
  const float* wp = (const float*)d_in[8];
  const float* bp = (const float*)d_in[9];

  char* ws = (char*)d_ws;
  bf16_t* w1img = (bf16_t*)(ws);           // 72 KB (64KB packed swz + 8KB ext)
  bf16_t* wpT2  = (bf16_t*)(ws + 73728);   // 256 KB (256 x 512)
  float*  bfold = (float*)(ws + 335872);   // 1 KB
  float*  b1fold = (float*)(ws + 336896);  // 1 KB
  bf16_t* cat   = (bf16_t*)(ws + 337920);  // 8192*512 bf16 = 8 MB
  float* out = (float*)d_out;

  if (ws_size < (size_t)(337920 + 8192 * 512 * 2)) return;  // workspace guard

  prep<<<dim3(113), dim3(256), 0, stream>>>(
      w1, w2, wp, b1, b2, bp, w1img, wpT2, bfold, b1fold);
  edge_mlp<<<dim3(1024), dim3(512), 0, stream>>>(pos, sup_idx, src_idx, w1img, b1fold, cat);
  proj<<<dim3(256, 2), dim3(256), 0, stream>>>(cat, wpT2, bfold, out);
}

// Round 14
// 78.272 us; speedup vs baseline: 2.0979x; 2.0979x over previous
//
#include <hip/hip_runtime.h>
#include <hip/hip_bf16.h>

typedef __bf16 bf16_t;
typedef bf16_t bf16x8 __attribute__((ext_vector_type(8)));
typedef float f32x16 __attribute__((ext_vector_type(16)));

// 10000^(-i/32) = 10^(-i/8), i = 0..15
constexpr float OMG[16] = {
    1.0f,        0.74989421f, 0.56234133f, 0.42169650f,
    0.31622777f, 0.23713737f, 0.17782794f, 0.13335214f,
    0.1f,        0.074989421f, 0.056234133f, 0.042169650f,
    0.031622777f, 0.023713737f, 0.017782794f, 0.013335214f};

__device__ __forceinline__ f32x16 mfma_bf16(bf16x8 a, bf16x8 b, f32x16 c) {
  return __builtin_amdgcn_mfma_f32_32x32x16_bf16(a, b, c, 0, 0, 0);
}

// packed k-index pk = 32d + 16m2 + (8hi+e)  <->  orig k = 64d + 32m2 + (8hi+e)
__device__ __forceinline__ int orig_k(int pk) {
  return 64 * (pk >> 5) + 32 * ((pk >> 4) & 1) + (pk & 15);
}

// ---- fused prep (113 blocks): same as round 13
__global__ __launch_bounds__(256) void prep(
    const float* __restrict__ w1, const float* __restrict__ w2,
    const float* __restrict__ wp, const float* __restrict__ b1,
    const float* __restrict__ b2, const float* __restrict__ bp,
    bf16_t* __restrict__ w1img, bf16_t* __restrict__ wpT2,
    float* __restrict__ bfold, float* __restrict__ b1fold) {
  __shared__ float T[256][33];
  const int bid = blockIdx.x;
  const int tid = threadIdx.x;

  if (bid < 8) {
    const int n0 = bid * 32;
#pragma unroll
    for (int it = 0; it < 16; ++it) {
      const int pk = it * 8 + (tid >> 5);
      T[pk][tid & 31] = w1[orig_k(pk) * 256 + n0 + (tid & 31)];
    }
    __syncthreads();
    const int n_off = tid & 31;
    const int n = n0 + n_off;
#pragma unroll
    for (int q = 0; q < 2; ++q) {
      const int slot = (tid >> 5) + 8 * q;  // 0..15
      bf16x8 v;
#pragma unroll
      for (int e = 0; e < 8; ++e) v[e] = (bf16_t)T[slot * 8 + e][n_off];
      *(bf16x8*)((char*)w1img + n * 256 + ((slot ^ (n & 15)) << 4)) = v;
    }
  } else if (bid == 8) {
    const int n = tid;
    float vl[4];
    float bf1 = b1[n];
#pragma unroll
    for (int d = 0; d < 4; ++d) {
      float s = 0.f;
#pragma unroll
      for (int i = 0; i < 16; ++i)
        s = fmaf(0.01f * OMG[i], w1[(64 * d + 16 + i) * 256 + n], s);
      vl[d] = s;
#pragma unroll
      for (int i = 0; i < 16; ++i) bf1 += w1[(64 * d + 48 + i) * 256 + n];
    }
    bf16_t* ext = w1img + 32768 + n * 16;
#pragma unroll
    for (int e = 0; e < 4; ++e) ext[e] = (bf16_t)vl[e];
#pragma unroll
    for (int e = 4; e < 16; ++e) ext[e] = (bf16_t)0.0f;
    b1fold[n] = bf1;
  } else if (bid < 17) {
    const int band = (bid - 9) * 32;
#pragma unroll
    for (int it = 0; it < 32; ++it)
      T[tid][it] = wp[(256 + band + it) * 256 + tid];
    __syncthreads();
    const int o = tid;
#pragma unroll
    for (int g = 0; g < 4; ++g) {
      bf16x8 v;
#pragma unroll
      for (int e = 0; e < 8; ++e) v[e] = (bf16_t)T[o][g * 8 + e];
      *(bf16x8*)(wpT2 + o * 512 + 256 + band + g * 8) = v;
    }
  } else if (bid < 81) {
    const int t2 = bid - 17;
    const int o0 = (t2 >> 3) * 32, j0 = (t2 & 7) * 32;
#pragma unroll
    for (int it = 0; it < 32; ++it) {
      const int n = it * 8 + (tid >> 5);
      T[n][tid & 31] = wp[n * 256 + o0 + (tid & 31)];
    }
    __syncthreads();
    const int o_off = tid & 31, jb = tid >> 5;
    float a4[4] = {0.f, 0.f, 0.f, 0.f};
    for (int n = 0; n < 256; ++n) {
      const float wv = T[n][o_off];
#pragma unroll
      for (int q = 0; q < 4; ++q)
        a4[q] = fmaf(w2[(j0 + jb + 8 * q) * 256 + n], wv, a4[q]);
    }
#pragma unroll
    for (int q = 0; q < 4; ++q)
      wpT2[(o0 + o_off) * 512 + j0 + jb + 8 * q] = (bf16_t)a4[q];
  } else {
    const int o = (bid - 81) * 8 + (tid >> 5);
    const int kl = (tid & 31) * 8;
    float s = 0.f;
#pragma unroll
    for (int k = 0; k < 8; ++k) s += b2[kl + k] * wp[(kl + k) * 256 + o];
    s += __shfl_xor(s, 16); s += __shfl_xor(s, 8); s += __shfl_xor(s, 4);
    s += __shfl_xor(s, 2); s += __shfl_xor(s, 1);
    if ((tid & 31) == 0) bfold[o] = s + bp[o];
  }
}

// ---- edge kernel: 512 thr = 4 pairs; pair = 1 supernode; wave = 128 out cols.
// acc[4]=64 AGPR; live arch state during MFMA kept minimal to fit the
// 128-reg unified budget at 4 waves/SIMD (r13 spill lesson). All epilogue
// constants (b1fold, sup-embed omegas) recomputed AFTER the MFMA loop.
__global__ __launch_bounds__(512, 4) void edge_mlp(
    const float* __restrict__ pos, const int* __restrict__ sup_idx,
    const int* __restrict__ src_idx,
    const bf16_t* __restrict__ w1img, const float* __restrict__ b1fold,
    bf16_t* __restrict__ cat) {
  __shared__ __attribute__((aligned(16))) bf16_t Bs[36864];  // 72 KiB

  const int tid = threadIdx.x;

  // one-time linear stage of the pre-swizzled image (64KB B' + 8KB ext)
  {
    const bf16x8* src8 = (const bf16x8*)w1img;
    bf16x8* dst8 = (bf16x8*)Bs;
#pragma unroll
    for (int it = 0; it < 9; ++it) {
      const int idx = it * 512 + tid;
      dst8[idx] = src8[idx];
    }
  }

  const int l = tid & 63, w = tid >> 6;
  const int pair = w >> 1, half = w & 1;
  const int hi = l >> 5, lc = l & 31;
  const int s = blockIdx.x * 4 + pair;

  const int si = sup_idx[s];
  const int srci = src_idx[s * 32 + lc];
  const float dx = pos[si * 3 + 0] - pos[srci * 3 + 0];
  const float dy = pos[si * 3 + 1] - pos[srci * 3 + 1];
  const float dz = pos[si * 3 + 2] - pos[srci * 3 + 2];
  const float mg = sqrtf(dx * dx + dy * dy + dz * dz);
  const float rv[4] = {dx, dy, dz, mg};

  float omg[8];
#pragma unroll
  for (int e = 0; e < 8; ++e) omg[e] = hi ? OMG[8 + e] : OMG[e];

  __syncthreads();

  f32x16 acc[4];
#pragma unroll
  for (int nt = 0; nt < 4; ++nt)
#pragma unroll
    for (int p = 0; p < 16; ++p) acc[nt][p] = 0.0f;

  const char* Bb = (const char*)Bs;
  const int sxor = (lc & 15) << 4;
  const int rowbase = (128 * half + lc) * 256;  // + nt*8192

  // rank-4 ext step
  {
    bf16x8 aext;
#pragma unroll
    for (int e = 0; e < 8; ++e)
      aext[e] = (hi == 0 && e < 4) ? (bf16_t)rv[e] : (bf16_t)0.0f;
    const char* eb = Bb + 65536 + (128 * half + lc) * 32 + hi * 16;
#pragma unroll
    for (int nt = 0; nt < 4; ++nt) {
      bf16x8 be = *(const bf16x8*)(eb + nt * 1024);
      acc[nt] = mfma_bf16(aext, be, acc[nt]);
    }
  }

#pragma unroll
  for (int d = 0; d < 4; ++d) {
    float ang[8];
#pragma unroll
    for (int e = 0; e < 8; ++e) ang[e] = rv[d] * omg[e];
    bf16x8 a_sin, a_cos;
#pragma unroll
    for (int e = 0; e < 8; ++e) a_sin[e] = (bf16_t)__sinf(ang[e]);
#pragma unroll
    for (int e = 0; e < 8; ++e) a_cos[e] = (bf16_t)__cosf(ang[e]);

    const int ko_sin = ((4 * d + hi) << 4) ^ sxor;
    const int ko_cos = ((4 * d + 2 + hi) << 4) ^ sxor;
    {
      bf16x8 b0 = *(const bf16x8*)(Bb + rowbase + 0 * 8192 + ko_sin);
      bf16x8 b1_ = *(const bf16x8*)(Bb + rowbase + 1 * 8192 + ko_sin);
      bf16x8 b2_ = *(const bf16x8*)(Bb + rowbase + 2 * 8192 + ko_sin);
      bf16x8 b3 = *(const bf16x8*)(Bb + rowbase + 3 * 8192 + ko_sin);
      acc[0] = mfma_bf16(a_sin, b0, acc[0]);
      acc[1] = mfma_bf16(a_sin, b1_, acc[1]);
      acc[2] = mfma_bf16(a_sin, b2_, acc[2]);
      acc[3] = mfma_bf16(a_sin, b3, acc[3]);
    }
    {
      bf16x8 b0 = *(const bf16x8*)(Bb + rowbase + 0 * 8192 + ko_cos);
      bf16x8 b1_ = *(const bf16x8*)(Bb + rowbase + 1 * 8192 + ko_cos);
      bf16x8 b2_ = *(const bf16x8*)(Bb + rowbase + 2 * 8192 + ko_cos);
      bf16x8 b3 = *(const bf16x8*)(Bb + rowbase + 3 * 8192 + ko_cos);
      acc[0] = mfma_bf16(a_cos, b0, acc[0]);
      acc[1] = mfma_bf16(a_cos, b1_, acc[1]);
      acc[2] = mfma_bf16(a_cos, b2_, acc[2]);
      acc[3] = mfma_bf16(a_cos, b3, acc[3]);
    }
  }

  // trimmed gelu + segment mean -> cat[s, 128*half .. +128)
  const float C2 = -0.10296644f, C0 = -2.3022765f;
#pragma unroll
  for (int nt = 0; nt < 4; ++nt) {
    const float bi = b1fold[128 * half + 32 * nt + lc];  // loaded here, not carried
    float ssum = 0.0f;
#pragma unroll
    for (int p = 0; p < 16; p += 2) {
      const float x0 = acc[nt][p] + bi;
      const float x1 = acc[nt][p + 1] + bi;
      const float t0 = fmaf(x0 * x0, C2, C0), t1 = fmaf(x1 * x1, C2, C0);
      const float e0 = exp2f(x0 * t0), e1 = exp2f(x1 * t1);
      const float r0 = __builtin_amdgcn_rcpf(e0 + 1.0f);
      const float r1 = __builtin_amdgcn_rcpf(e1 + 1.0f);
      ssum = fmaf(x0, r0, ssum);
      ssum = fmaf(x1, r1, ssum);
    }
    ssum += __shfl_xor(ssum, 32);
    if (hi == 0)
      cat[s * 512 + 128 * half + 32 * nt + lc] = (bf16_t)(ssum * 0.03125f);
  }

  // sup-embed (recomputed constants; only si carried across the MFMA loop)
#pragma unroll
  for (int q = 0; q < 2; ++q) {
    const int col = 128 * half + l + 64 * q;
    float v = 0.0f;
    if (col < 252) {
      const int d = (col >= 84 ? 1 : 0) + (col >= 168 ? 1 : 0);
      const int t3 = col - 84 * d;
      const int sc2 = (t3 >= 42) ? 1 : 0;
      const float om = __expf(-0.21929381838038533f * (float)(t3 - 42 * sc2));
      const float pd = pos[si * 3 + d];
      const float ang = pd * om;
      v = sc2 ? __cosf(ang) : __sinf(ang);
    }
    cat[s * 512 + 256 + col] = (bf16_t)v;
  }
}

// ---- fused projection: out = cat(8192x512) @ wpT2^T + bfold -> fp32
__global__ __launch_bounds__(256) void proj(
    const bf16_t* __restrict__ cat, const bf16_t* __restrict__ wpT2,
    const float* __restrict__ bfold, float* __restrict__ out) {
  const int tid = threadIdx.x;
  const int l = tid & 63, w = tid >> 6;
  const int hi = l >> 5, lc = l & 31;
  const int rm = blockIdx.x * 32;
  const int cn = blockIdx.y * 128 + w * 32;
  const int r0 = rm + lc;
  const int c0 = cn + lc;

  f32x16 a0;
#pragma unroll
  for (int p = 0; p < 16; ++p) a0[p] = 0.f;
#pragma unroll 8
  for (int kk = 0; kk < 32; ++kk) {
    int k0 = kk * 16 + 8 * hi;
    bf16x8 fa0 = *(const bf16x8*)(cat + r0 * 512 + k0);
    bf16x8 fb = *(const bf16x8*)(wpT2 + c0 * 512 + k0);
    a0 = mfma_bf16(fa0, fb, a0);
  }
  float bias = bfold[c0];
#pragma unroll
  for (int rr = 0; rr < 16; ++rr) {
    int rowo = (rr & 3) + 8 * (rr >> 2) + 4 * hi;
    out[(rm + rowo) * 256 + c0] = a0[rr] + bias;
  }
}

extern "C" void kernel_launch(void* const* d_in, const int* in_sizes, int n_in,
                              void* d_out, int out_size, void* d_ws, size_t ws_size,
                              hipStream_t stream) {
  const float* pos = (const float*)d_in[0];
  const int* sup_idx = (const int*)d_in[1];
  const int* src_idx = (const int*)d_in[2];
  // d_in[3] = dst_seg: repeat(arange(NSUP), DEG) by construction; not needed
  const float* w1 = (const float*)d_in[4];
  const float* b1 = (const float*)d_in[5];
  const float* w2 = (const float*)d_in[6];
  const float* b2 = (const float*)d_in[7];
  const float* wp = (const float*)d_in[8];
  const float* bp = (const float*)d_in[9];

  char* ws = (char*)d_ws;
  bf16_t* w1img = (bf16_t*)(ws);           // 72 KB (64KB packed swz + 8KB ext)
  bf16_t* wpT2  = (bf16_t*)(ws + 73728);   // 256 KB (256 x 512)
  float*  bfold = (float*)(ws + 335872);   // 1 KB
  float*  b1fold = (float*)(ws + 336896);  // 1 KB
  bf16_t* cat   = (bf16_t*)(ws + 337920);  // 8192*512 bf16 = 8 MB
  float* out = (float*)d_out;

  if (ws_size < (size_t)(337920 + 8192 * 512 * 2)) return;  // workspace guard

  prep<<<dim3(113), dim3(256), 0, stream>>>(
      w1, w2, wp, b1, b2, bp, w1img, wpT2, bfold, b1fold);
  edge_mlp<<<dim3(2048), dim3(512), 0, stream>>>(pos, sup_idx, src_idx, w1img, b1fold, cat);
  proj<<<dim3(256, 2), dim3(256), 0, stream>>>(cat, wpT2, bfold, out);
}